// Round 12
// baseline (187.018 us; speedup 1.0000x reference)
//
#include <hip/hip_runtime.h>
#include <hip/hip_bf16.h>
#include <math.h>

// ---------------------------------------------------------------------------
// CausalSelfAttention: B=2, S=2048, D=1024, H=16, Hd=64. f32 in / f32 out.
// R27 = R26 (gemm T1 swizzle + fused cvt_rope, 178.7us) + attn Psh ELIMINATED:
// the P C-layout->A-layout transpose is a 4x4 quad-exchange done in-register
// via 16 __shfl + 8 cndmask (derived from the verified MFMA layouts:
// pa0 = pk[quad>>1] from lanes s0=li+((quad&1)<<5), s1=s0+16; pa1 = pk[2+..]).
// Removes 4 ds_write_b64 + lgkmcnt(0) sync + 2 ds_read_b128 + 9.2KB LDS ->
// LDS 18432B -> 8 blocks/CU (32 waves, was ~5/20) = 2x latency hiding.
// P bits + rsum kept bit-identical to R17 (truncation) so absmax isolates
// the permute. Staging/barriers/MFMA order untouched (R25 lesson).
// ---------------------------------------------------------------------------

typedef short bfrag __attribute__((ext_vector_type(8)));   // 8 bf16 = 4 VGPR
typedef float f32x4 __attribute__((ext_vector_type(4)));

__device__ __forceinline__ float bf2f(ushort u) {
    union { uint i; float f; } v; v.i = ((uint)u) << 16; return v.f;
}
__device__ __forceinline__ ushort f2bf(float f) {
    union { uint i; float f; } v; v.f = f;
    uint u = v.i;
    return (ushort)((u + 0x7fffu + ((u >> 16) & 1u)) >> 16);  // RNE
}

#define MFMA16 __builtin_amdgcn_mfma_f32_16x16x32_bf16

__device__ __forceinline__ void gl_lds16(const ushort* g, ushort* l) {
    __builtin_amdgcn_global_load_lds(
        (const __attribute__((address_space(1))) void*)g,
        (__attribute__((address_space(3))) void*)l, 16, 0, 0);
}

// ---------------------------------------------------------------------------
// Kernel 0: fused f32->bf16 convert + rope table.
// Blocks [0,3584): cvt (xb = x; wb = [Wq;Wkv]). Blocks [3584,3840): rope.
// ---------------------------------------------------------------------------
__global__ __launch_bounds__(256)
void cvt_rope(const float* __restrict__ x, const float* __restrict__ wq,
              const float* __restrict__ wkv, ushort* __restrict__ xb,
              ushort* __restrict__ wb, float2* __restrict__ tab)
{
    if (blockIdx.x >= 3584) {
        // rope table: tab[s][fi] = (cos,sin)(s * 10000^(-fi/32))
        int t  = ((int)blockIdx.x - 3584) * 256 + threadIdx.x;   // 65536
        int fi = t & 31, s = t >> 5;
        float invf = (float)exp((double)fi * -0.28782313662425574);
        float thf  = (float)s * invf;
        const double TWO_PI = 6.283185307179586476925287;
        double th = (double)thf;
        double kq = __builtin_rint(th * (1.0 / TWO_PI));
        float r = (float)(th - kq * TWO_PI);
        tab[t] = make_float2(cosf(r), sinf(r));
        return;
    }
    const size_t NX = 4096u * 1024u, NWQ = 1024u * 1024u;
    size_t i8 = ((size_t)blockIdx.x * 256 + threadIdx.x) * 8;
    const float* src;
    ushort* dst;
    if (i8 < NX) { src = x + i8; dst = xb + i8; }
    else {
        size_t j = i8 - NX;
        dst = wb + j;
        src = (j < NWQ) ? (wq + j) : (wkv + (j - NWQ));
    }
    float4 a = *(const float4*)(src);
    float4 c = *(const float4*)(src + 4);
    ushort u[8];
    u[0] = f2bf(a.x); u[1] = f2bf(a.y); u[2] = f2bf(a.z); u[3] = f2bf(a.w);
    u[4] = f2bf(c.x); u[5] = f2bf(c.y); u[6] = f2bf(c.z); u[7] = f2bf(c.w);
    *(uint4*)dst = *(uint4*)u;
}

// ---------------------------------------------------------------------------
// Kernel 1 (R26): QKV GEMM, BK=64, swizzled LDS, fused RoPE, T1 XCD swizzle.
// ---------------------------------------------------------------------------
__global__ __launch_bounds__(256)
void gemm_qkv(const ushort* __restrict__ xb, const ushort* __restrict__ wb,
              const float2* __restrict__ tab, ushort* __restrict__ Qb,
              ushort* __restrict__ Kb, ushort* __restrict__ Vt)
{
    __shared__ ushort Ash[128][64];
    __shared__ ushort Bsh[128][64];

    const int tid  = threadIdx.x;
    const int lane = tid & 63, wv = tid >> 6;
    const int quad = lane >> 4, li = lane & 15;

    // T1 XCD-aware remap: XCD c owns x' in [4c,4c+4), all y'
    const int lin  = (int)blockIdx.y * 32 + (int)blockIdx.x;
    const int lin2 = (lin & 7) * 96 + (lin >> 3);
    const int m0 = ((lin2 / 96) * 4 + (lin2 & 3)) * 128;
    const int n0 = ((lin2 % 96) >> 2) * 128;

    f32x4 acc[2][8];
#pragma unroll
    for (int mi = 0; mi < 2; mi++)
#pragma unroll
        for (int j = 0; j < 8; j++) acc[mi][j] = (f32x4){0.f, 0.f, 0.f, 0.f};

    const int r8  = lane >> 3;
    const int gch = ((lane & 7) ^ r8) * 8;
    const ushort* gA = xb + (size_t)(m0 + wv * 32 + r8) * 1024 + gch;
    const ushort* gB = wb + (size_t)(n0 + wv * 32 + r8) * 1024 + gch;

    for (int k0 = 0; k0 < 1024; k0 += 64) {
        __syncthreads();
#pragma unroll
        for (int c = 0; c < 4; c++) {
            gl_lds16(gA + (size_t)(c * 8) * 1024 + k0, &Ash[wv * 32 + c * 8][0]);
            gl_lds16(gB + (size_t)(c * 8) * 1024 + k0, &Bsh[wv * 32 + c * 8][0]);
        }
        __syncthreads();

        const int sw = li & 7;
#pragma unroll
        for (int ks = 0; ks < 2; ks++) {
            bfrag af[2], bf[8];
#pragma unroll
            for (int mi = 0; mi < 2; mi++)
                af[mi] = *(const bfrag*)
                    &Ash[wv * 32 + mi * 16 + li][(((ks << 2) | quad) ^ sw) * 8];
#pragma unroll
            for (int j = 0; j < 8; j++)
                bf[j] = *(const bfrag*)
                    &Bsh[j * 16 + li][(((ks << 2) | quad) ^ sw) * 8];
#pragma unroll
            for (int mi = 0; mi < 2; mi++)
#pragma unroll
                for (int j = 0; j < 8; j++)
                    acc[mi][j] = MFMA16(af[mi], bf[j], acc[mi][j], 0, 0, 0);
        }
    }

    if (n0 < 1024) {
        const int hbase = n0 >> 6;
#pragma unroll
        for (int mi = 0; mi < 2; mi++)
#pragma unroll
            for (int r = 0; r < 4; r++) {
                int m = m0 + wv * 32 + mi * 16 + quad * 4 + r;
                int bb = m >> 11, s = m & 2047;
                float2 t0 = tab[s * 32 + li];
                float2 t1 = tab[s * 32 + li + 16];
#pragma unroll
                for (int j = 0; j < 8; j++) {
                    float v  = acc[mi][j][r];
                    float vp = acc[mi][j ^ 2][r];
                    float2 tt = (j & 1) ? t1 : t0;
                    float rh = (j & 2) ? vp : -vp;
                    int h = hbase + (j >> 2), hd = (j & 3) * 16 + li;
                    Qb[(size_t)((bb * 16 + h) * 2048 + s) * 64 + hd] =
                        f2bf(v * tt.x + rh * tt.y);
                }
            }
    } else {
        const int h = (n0 - 1024) >> 7;
        const int li2 = li >> 1;
        if ((li & 1) == 0) {
#pragma unroll
            for (int mi = 0; mi < 2; mi++)
#pragma unroll
                for (int r = 0; r < 4; r++) {
                    int m = m0 + wv * 32 + mi * 16 + quad * 4 + r;
                    int bb = m >> 11, s = m & 2047;
                    float2 tt4[4];
#pragma unroll
                    for (int jj = 0; jj < 4; jj++)
                        tt4[jj] = tab[s * 32 + jj * 8 + li2];
#pragma unroll
                    for (int j = 0; j < 8; j++) {
                        float v  = acc[mi][j][r];
                        float vp = acc[mi][j ^ 4][r];
                        float2 tt = tt4[j & 3];
                        float rh = (j & 4) ? vp : -vp;
                        int hd = j * 8 + li2;
                        Kb[(size_t)((bb * 16 + h) * 2048 + s) * 64 + hd] =
                            f2bf(v * tt.x + rh * tt.y);
                    }
                }
        } else {
#pragma unroll
            for (int mi = 0; mi < 2; mi++) {
                int m4 = m0 + wv * 32 + mi * 16 + quad * 4;
                int bb = m4 >> 11, s0 = m4 & 2047;
#pragma unroll
                for (int j = 0; j < 8; j++) {
                    int hd = j * 8 + li2;
                    ushort u4[4];
#pragma unroll
                    for (int r = 0; r < 4; r++) u4[r] = f2bf(acc[mi][j][r]);
                    *(ushort4*)&Vt[(size_t)((bb * 16 + h) * 64 + hd) * 2048 + s0] =
                        *(ushort4*)u4;
                }
            }
        }
    }
}

// ---------------------------------------------------------------------------
// Kernel 2 (R27): R17 attn with the P transpose moved from LDS (Psh) to
// in-register shfl. Everything else (staging, barriers, MFMA order, mask,
// truncation-consistent rsum, qt swizzle) is R17-verbatim.
// pa0 slots (k=quad*8+c): c0..3 from lane s0=li+((quad&1)<<5) pk[quad>>1],
// c4..7 from s1=s0+16 same pk; pa1 same lanes, pk[2+(quad>>1)].
// Two dest quads want different pk from one source -> 2 shfl + cndmask per
// 32b slot: 16 shfl + 8 select total.
// ---------------------------------------------------------------------------
__global__ __launch_bounds__(256)
void attn(const ushort* __restrict__ Qb, const ushort* __restrict__ Kb,
          const ushort* __restrict__ Vt, float* __restrict__ out)
{
    __shared__ ushort Ksh[64][72];
    __shared__ ushort Vsh[64][72];

    const int tid  = threadIdx.x;
    const int lane = tid & 63, w = tid >> 6;
    const int quad = lane >> 4, li = lane & 15;
    const int qt = ((31 - (int)blockIdx.x) + (int)blockIdx.y) & 31;
    const int bh = blockIdx.y;
    const int b = bh >> 4, h = bh & 15;

    const int qrow = qt * 64 + w * 16 + li;      // this lane's q (swapped layout)
    const ushort* qp = Qb + (size_t)(bh * 2048 + qrow) * 64;
    bfrag qa0 = *(const bfrag*)(qp + quad * 8);
    bfrag qa1 = *(const bfrag*)(qp + quad * 8 + 32);

    f32x4 o[4];
#pragma unroll
    for (int j = 0; j < 4; j++) o[j] = (f32x4){0.f, 0.f, 0.f, 0.f};
    float lrow = 0.f;                            // running denom for q = li

    const int srow = tid >> 2, sc0 = (tid & 3) * 16;
    const ushort* kbase = Kb + (size_t)bh * 2048 * 64;
    const ushort* vbase = Vt + (size_t)bh * 64 * 2048;

    // P-transpose source lanes (constant per thread)
    const int ps0 = li + ((quad & 1) << 5);
    const int ps1 = ps0 + 16;
    const bool qlo = (quad < 2);

    // preload kt=0 (16 VGPRs of prefetch state — no spill at this size)
    uint4 ka, kb_, va, vb_;
    {
        const ushort* gk = kbase + (size_t)srow * 64 + sc0;
        ka  = *(const uint4*)gk;
        kb_ = *(const uint4*)(gk + 8);
        const ushort* gv = vbase + (size_t)srow * 2048 + sc0;
        va  = *(const uint4*)gv;
        vb_ = *(const uint4*)(gv + 8);
    }

    const float C = 0.125f * 1.4426950408889634f;   // scale * log2(e)

    for (int kt = 0; kt <= qt; ++kt) {
        __syncthreads();
        *(uint4*)&Ksh[srow][sc0]     = ka;
        *(uint4*)&Ksh[srow][sc0 + 8] = kb_;
        *(uint4*)&Vsh[srow][sc0]     = va;
        *(uint4*)&Vsh[srow][sc0 + 8] = vb_;
        __syncthreads();

        if (kt < qt) {     // prefetch next tile; latency hidden by compute
            const ushort* gk = kbase + (size_t)((kt + 1) * 64 + srow) * 64 + sc0;
            ka  = *(const uint4*)gk;
            kb_ = *(const uint4*)(gk + 8);
            const ushort* gv = vbase + (size_t)srow * 2048 + (kt + 1) * 64 + sc0;
            va  = *(const uint4*)gv;
            vb_ = *(const uint4*)(gv + 8);
        }

        // --- scores, swapped: sc[j][r] = S[k = kt*64+j*16+quad*4+r][q = li] ---
        f32x4 sc[4];
        __builtin_amdgcn_s_setprio(1);
#pragma unroll
        for (int j = 0; j < 4; j++) {
            bfrag kb0 = *(const bfrag*)&Ksh[j * 16 + li][quad * 8];
            bfrag kb1 = *(const bfrag*)&Ksh[j * 16 + li][quad * 8 + 32];
            f32x4 z = (f32x4){0.f, 0.f, 0.f, 0.f};
            z = MFMA16(kb0, qa0, z, 0, 0, 0);
            z = MFMA16(kb1, qa1, z, 0, 0, 0);
            sc[j] = z;
        }
        __builtin_amdgcn_s_setprio(0);

        // --- causal mask: only the diagonal tile needs it ---
        if (kt == qt) {
#pragma unroll
            for (int j = 0; j < 4; j++) {
                int kg0 = kt * 64 + j * 16 + quad * 4;
#pragma unroll
                for (int r = 0; r < 4; r++)
                    sc[j][r] = (kg0 + r <= qrow) ? sc[j][r] : -3.0e38f;
            }
        }

        // --- P = exp2(sc*C); pack per-j into 2 uints (bits == R17 Psh) ---
        float rs = 0.f;
        uint pl[4], ph[4];                      // pk_j = {r0,r1} / {r2,r3}
#pragma unroll
        for (int j = 0; j < 4; j++) {
            ushort pk[4];
#pragma unroll
            for (int r = 0; r < 4; r++) {
                float pv = exp2f(sc[j][r] * C);
                uint pu = __float_as_uint(pv);
                pk[r] = (ushort)(pu >> 16);
                rs += __uint_as_float(pu & 0xffff0000u);  // consistent w/ P
            }
            pl[j] = (uint)pk[0] | ((uint)pk[1] << 16);
            ph[j] = (uint)pk[2] | ((uint)pk[3] << 16);
        }
        // complete row-sum for q=li across the 4 quads
        rs += __shfl_xor(rs, 16);
        rs += __shfl_xor(rs, 32);
        lrow += rs;

        // --- P transpose to A-layout: 16 shfl + 8 cndmask, no LDS ---
        union { uint u[4]; bfrag f; } pa0u, pa1u;
        {
            uint t0, t1;
            t0 = __shfl(pl[0], ps0); t1 = __shfl(pl[1], ps0);
            pa0u.u[0] = qlo ? t0 : t1;
            t0 = __shfl(ph[0], ps0); t1 = __shfl(ph[1], ps0);
            pa0u.u[1] = qlo ? t0 : t1;
            t0 = __shfl(pl[0], ps1); t1 = __shfl(pl[1], ps1);
            pa0u.u[2] = qlo ? t0 : t1;
            t0 = __shfl(ph[0], ps1); t1 = __shfl(ph[1], ps1);
            pa0u.u[3] = qlo ? t0 : t1;
            t0 = __shfl(pl[2], ps0); t1 = __shfl(pl[3], ps0);
            pa1u.u[0] = qlo ? t0 : t1;
            t0 = __shfl(ph[2], ps0); t1 = __shfl(ph[3], ps0);
            pa1u.u[1] = qlo ? t0 : t1;
            t0 = __shfl(pl[2], ps1); t1 = __shfl(pl[3], ps1);
            pa1u.u[2] = qlo ? t0 : t1;
            t0 = __shfl(ph[2], ps1); t1 = __shfl(ph[3], ps1);
            pa1u.u[3] = qlo ? t0 : t1;
        }
        bfrag pa0 = pa0u.f;
        bfrag pa1 = pa1u.f;

        __builtin_amdgcn_s_setprio(1);
#pragma unroll
        for (int j = 0; j < 4; j++) {
            bfrag vb0 = *(const bfrag*)&Vsh[j * 16 + li][quad * 8];
            bfrag vb1 = *(const bfrag*)&Vsh[j * 16 + li][quad * 8 + 32];
            o[j] = MFMA16(pa0, vb0, o[j], 0, 0, 0);
            o[j] = MFMA16(pa1, vb1, o[j], 0, 0, 0);
        }
        __builtin_amdgcn_s_setprio(0);
    }

    // epilogue: redistribute l (held at lane li == q) to q = quad*4+r
    float lf[4];
#pragma unroll
    for (int r = 0; r < 4; r++)
        lf[r] = __shfl(lrow, (lane & 48) + quad * 4 + r);

#pragma unroll
    for (int j = 0; j < 4; j++)
#pragma unroll
        for (int r = 0; r < 4; r++) {
            int s = qt * 64 + w * 16 + quad * 4 + r;
            out[(size_t)(b * 2048 + s) * 1024 + h * 64 + j * 16 + li] =
                o[j][r] / lf[r];
        }
}

// ---------------------------------------------------------------------------
extern "C" void kernel_launch(void* const* d_in, const int* in_sizes, int n_in,
                              void* d_out, int out_size, void* d_ws, size_t ws_size,
                              hipStream_t stream)
{
    (void)in_sizes; (void)n_in; (void)out_size; (void)ws_size;
    const float* x   = (const float*)d_in[0];   // (2,2048,1024) f32
    const float* wq  = (const float*)d_in[1];   // (1024,1024)  f32
    const float* wkv = (const float*)d_in[2];   // (2048,1024)  f32
    // d_in[3] = causal mask — computed analytically

    ushort* xb = (ushort*)d_ws;                       // 4096x1024 bf16
    ushort* wb = xb + (size_t)4096 * 1024;            // 3072x1024 bf16
    float2* tab = (float2*)(wb + (size_t)3072 * 1024); // 2048x32 (cos,sin)
    ushort* Qb = (ushort*)(tab + 65536);              // (B,H,S,Hd)
    ushort* Kb = Qb + (size_t)2 * 16 * 2048 * 64;     // (B,H,S,Hd)
    ushort* Vt = Kb + (size_t)2 * 16 * 2048 * 64;     // (B,H,Hd,S)
    float* out = (float*)d_out;                       // f32 output

    cvt_rope<<<3840, 256, 0, stream>>>(x, wq, wkv, xb, wb, tab);
    dim3 g1(32, 24);
    gemm_qkv<<<g1, 256, 0, stream>>>(xb, wb, tab, Qb, Kb, Vt);
    dim3 g4(32, 32);
    attn<<<g4, 256, 0, stream>>>(Qb, Kb, Vt, out);
}

// Round 13
// 173.971 us; speedup vs baseline: 1.0750x; 1.0750x over previous
//
#include <hip/hip_runtime.h>
#include <hip/hip_bf16.h>
#include <math.h>

// ---------------------------------------------------------------------------
// CausalSelfAttention: B=2, S=2048, D=1024, H=16, Hd=64. f32 in / f32 out.
// R28 = R26 (verified 178.7us: gemm T1 swizzle + fused cvt_rope + R17 attn)
// with ONE change: attn qt balance perfected. Co-resident blocks (same x,
// y spaced by 8) previously got qt summing 4*((x+y)&7)+48 -> per-CU work
// 52..80 tile-iters (mean 66). New: u=(x+y)&31 -> coset permutation
// sigma: i=u>>3, j=u&7 -> qt in {j, 15-j, 16+j, 31-j} so EVERY CU's four
// blocks sum to 62 (+4) = 66 exactly. Bijective per head (ranges 0-7,
// 8-15, 16-23, 24-31). R27 lesson logged: __shfl is ds_bpermute (DS pipe)
// -- in-register P transpose via shfl costs MORE than the Psh round-trip;
// and occupancy was grid-capped at 4 blocks/CU, not LDS-capped.
// ---------------------------------------------------------------------------

typedef short bfrag __attribute__((ext_vector_type(8)));   // 8 bf16 = 4 VGPR
typedef float f32x4 __attribute__((ext_vector_type(4)));

__device__ __forceinline__ float bf2f(ushort u) {
    union { uint i; float f; } v; v.i = ((uint)u) << 16; return v.f;
}
__device__ __forceinline__ ushort f2bf(float f) {
    union { uint i; float f; } v; v.f = f;
    uint u = v.i;
    return (ushort)((u + 0x7fffu + ((u >> 16) & 1u)) >> 16);  // RNE
}

#define MFMA16 __builtin_amdgcn_mfma_f32_16x16x32_bf16

__device__ __forceinline__ void gl_lds16(const ushort* g, ushort* l) {
    __builtin_amdgcn_global_load_lds(
        (const __attribute__((address_space(1))) void*)g,
        (__attribute__((address_space(3))) void*)l, 16, 0, 0);
}

// ---------------------------------------------------------------------------
// Kernel 0: fused f32->bf16 convert + rope table.
// Blocks [0,3584): cvt (xb = x; wb = [Wq;Wkv]). Blocks [3584,3840): rope.
// ---------------------------------------------------------------------------
__global__ __launch_bounds__(256)
void cvt_rope(const float* __restrict__ x, const float* __restrict__ wq,
              const float* __restrict__ wkv, ushort* __restrict__ xb,
              ushort* __restrict__ wb, float2* __restrict__ tab)
{
    if (blockIdx.x >= 3584) {
        // rope table: tab[s][fi] = (cos,sin)(s * 10000^(-fi/32))
        int t  = ((int)blockIdx.x - 3584) * 256 + threadIdx.x;   // 65536
        int fi = t & 31, s = t >> 5;
        float invf = (float)exp((double)fi * -0.28782313662425574);
        float thf  = (float)s * invf;
        const double TWO_PI = 6.283185307179586476925287;
        double th = (double)thf;
        double kq = __builtin_rint(th * (1.0 / TWO_PI));
        float r = (float)(th - kq * TWO_PI);
        tab[t] = make_float2(cosf(r), sinf(r));
        return;
    }
    const size_t NX = 4096u * 1024u, NWQ = 1024u * 1024u;
    size_t i8 = ((size_t)blockIdx.x * 256 + threadIdx.x) * 8;
    const float* src;
    ushort* dst;
    if (i8 < NX) { src = x + i8; dst = xb + i8; }
    else {
        size_t j = i8 - NX;
        dst = wb + j;
        src = (j < NWQ) ? (wq + j) : (wkv + (j - NWQ));
    }
    float4 a = *(const float4*)(src);
    float4 c = *(const float4*)(src + 4);
    ushort u[8];
    u[0] = f2bf(a.x); u[1] = f2bf(a.y); u[2] = f2bf(a.z); u[3] = f2bf(a.w);
    u[4] = f2bf(c.x); u[5] = f2bf(c.y); u[6] = f2bf(c.z); u[7] = f2bf(c.w);
    *(uint4*)dst = *(uint4*)u;
}

// ---------------------------------------------------------------------------
// Kernel 1 (R26): QKV GEMM, BK=64, swizzled LDS, fused RoPE, T1 XCD swizzle.
// ---------------------------------------------------------------------------
__global__ __launch_bounds__(256)
void gemm_qkv(const ushort* __restrict__ xb, const ushort* __restrict__ wb,
              const float2* __restrict__ tab, ushort* __restrict__ Qb,
              ushort* __restrict__ Kb, ushort* __restrict__ Vt)
{
    __shared__ ushort Ash[128][64];
    __shared__ ushort Bsh[128][64];

    const int tid  = threadIdx.x;
    const int lane = tid & 63, wv = tid >> 6;
    const int quad = lane >> 4, li = lane & 15;

    // T1 XCD-aware remap: XCD c owns x' in [4c,4c+4), all y'
    const int lin  = (int)blockIdx.y * 32 + (int)blockIdx.x;
    const int lin2 = (lin & 7) * 96 + (lin >> 3);
    const int m0 = ((lin2 / 96) * 4 + (lin2 & 3)) * 128;
    const int n0 = ((lin2 % 96) >> 2) * 128;

    f32x4 acc[2][8];
#pragma unroll
    for (int mi = 0; mi < 2; mi++)
#pragma unroll
        for (int j = 0; j < 8; j++) acc[mi][j] = (f32x4){0.f, 0.f, 0.f, 0.f};

    const int r8  = lane >> 3;
    const int gch = ((lane & 7) ^ r8) * 8;
    const ushort* gA = xb + (size_t)(m0 + wv * 32 + r8) * 1024 + gch;
    const ushort* gB = wb + (size_t)(n0 + wv * 32 + r8) * 1024 + gch;

    for (int k0 = 0; k0 < 1024; k0 += 64) {
        __syncthreads();
#pragma unroll
        for (int c = 0; c < 4; c++) {
            gl_lds16(gA + (size_t)(c * 8) * 1024 + k0, &Ash[wv * 32 + c * 8][0]);
            gl_lds16(gB + (size_t)(c * 8) * 1024 + k0, &Bsh[wv * 32 + c * 8][0]);
        }
        __syncthreads();

        const int sw = li & 7;
#pragma unroll
        for (int ks = 0; ks < 2; ks++) {
            bfrag af[2], bf[8];
#pragma unroll
            for (int mi = 0; mi < 2; mi++)
                af[mi] = *(const bfrag*)
                    &Ash[wv * 32 + mi * 16 + li][(((ks << 2) | quad) ^ sw) * 8];
#pragma unroll
            for (int j = 0; j < 8; j++)
                bf[j] = *(const bfrag*)
                    &Bsh[j * 16 + li][(((ks << 2) | quad) ^ sw) * 8];
#pragma unroll
            for (int mi = 0; mi < 2; mi++)
#pragma unroll
                for (int j = 0; j < 8; j++)
                    acc[mi][j] = MFMA16(af[mi], bf[j], acc[mi][j], 0, 0, 0);
        }
    }

    if (n0 < 1024) {
        const int hbase = n0 >> 6;
#pragma unroll
        for (int mi = 0; mi < 2; mi++)
#pragma unroll
            for (int r = 0; r < 4; r++) {
                int m = m0 + wv * 32 + mi * 16 + quad * 4 + r;
                int bb = m >> 11, s = m & 2047;
                float2 t0 = tab[s * 32 + li];
                float2 t1 = tab[s * 32 + li + 16];
#pragma unroll
                for (int j = 0; j < 8; j++) {
                    float v  = acc[mi][j][r];
                    float vp = acc[mi][j ^ 2][r];
                    float2 tt = (j & 1) ? t1 : t0;
                    float rh = (j & 2) ? vp : -vp;
                    int h = hbase + (j >> 2), hd = (j & 3) * 16 + li;
                    Qb[(size_t)((bb * 16 + h) * 2048 + s) * 64 + hd] =
                        f2bf(v * tt.x + rh * tt.y);
                }
            }
    } else {
        const int h = (n0 - 1024) >> 7;
        const int li2 = li >> 1;
        if ((li & 1) == 0) {
#pragma unroll
            for (int mi = 0; mi < 2; mi++)
#pragma unroll
                for (int r = 0; r < 4; r++) {
                    int m = m0 + wv * 32 + mi * 16 + quad * 4 + r;
                    int bb = m >> 11, s = m & 2047;
                    float2 tt4[4];
#pragma unroll
                    for (int jj = 0; jj < 4; jj++)
                        tt4[jj] = tab[s * 32 + jj * 8 + li2];
#pragma unroll
                    for (int j = 0; j < 8; j++) {
                        float v  = acc[mi][j][r];
                        float vp = acc[mi][j ^ 4][r];
                        float2 tt = tt4[j & 3];
                        float rh = (j & 4) ? vp : -vp;
                        int hd = j * 8 + li2;
                        Kb[(size_t)((bb * 16 + h) * 2048 + s) * 64 + hd] =
                            f2bf(v * tt.x + rh * tt.y);
                    }
                }
        } else {
#pragma unroll
            for (int mi = 0; mi < 2; mi++) {
                int m4 = m0 + wv * 32 + mi * 16 + quad * 4;
                int bb = m4 >> 11, s0 = m4 & 2047;
#pragma unroll
                for (int j = 0; j < 8; j++) {
                    int hd = j * 8 + li2;
                    ushort u4[4];
#pragma unroll
                    for (int r = 0; r < 4; r++) u4[r] = f2bf(acc[mi][j][r]);
                    *(ushort4*)&Vt[(size_t)((bb * 16 + h) * 64 + hd) * 2048 + s0] =
                        *(ushort4*)u4;
                }
            }
        }
    }
}

// ---------------------------------------------------------------------------
// Kernel 2 (R17 attn + R28 coset-balanced qt): causal flash attention,
// swapped-QK^T in-register softmax. 1 WG (256 thr) = (b,h) x 64-row Q-tile;
// wave w owns 16 rows (q = li). Scores via mfma(K,Q); row-sum = 16 reg adds
// + shfl_xor(16,32); P b64-spill to wave-private Psh, read back as A-frag.
// Mask diagonal-only; no-max exp2; truncation-consistent rsum. Two-barrier
// staging with register prefetch.
// qt: u=(x+y)&31, i=u>>3, j=u&7 -> {j, 15-j, 16+j, 31-j}; co-resident
// blocks (y spaced 8) get one qt from each range -> per-CU work = 66 exactly.
// ---------------------------------------------------------------------------
__global__ __launch_bounds__(256)
void attn(const ushort* __restrict__ Qb, const ushort* __restrict__ Kb,
          const ushort* __restrict__ Vt, float* __restrict__ out)
{
    __shared__ ushort Ksh[64][72];
    __shared__ ushort Vsh[64][72];
    __shared__ ushort Psh[4][16][72];

    const int tid  = threadIdx.x;
    const int lane = tid & 63, w = tid >> 6;
    const int quad = lane >> 4, li = lane & 15;

    // R28 coset-balanced q-tile assignment (see header)
    const int u  = ((int)blockIdx.x + (int)blockIdx.y) & 31;
    const int cj = u & 7, ci = u >> 3;
    const int qt = (ci == 0) ? cj : (ci == 1) ? (15 - cj)
                 : (ci == 2) ? (16 + cj) : (31 - cj);

    const int bh = blockIdx.y;
    const int b = bh >> 4, h = bh & 15;

    const int qrow = qt * 64 + w * 16 + li;      // this lane's q (swapped layout)
    const ushort* qp = Qb + (size_t)(bh * 2048 + qrow) * 64;
    bfrag qa0 = *(const bfrag*)(qp + quad * 8);
    bfrag qa1 = *(const bfrag*)(qp + quad * 8 + 32);

    f32x4 o[4];
#pragma unroll
    for (int j = 0; j < 4; j++) o[j] = (f32x4){0.f, 0.f, 0.f, 0.f};
    float lrow = 0.f;                            // running denom for q = li

    const int srow = tid >> 2, sc0 = (tid & 3) * 16;
    const ushort* kbase = Kb + (size_t)bh * 2048 * 64;
    const ushort* vbase = Vt + (size_t)bh * 64 * 2048;

    // preload kt=0 (16 VGPRs of prefetch state — no spill at this size)
    uint4 ka, kb_, va, vb_;
    {
        const ushort* gk = kbase + (size_t)srow * 64 + sc0;
        ka  = *(const uint4*)gk;
        kb_ = *(const uint4*)(gk + 8);
        const ushort* gv = vbase + (size_t)srow * 2048 + sc0;
        va  = *(const uint4*)gv;
        vb_ = *(const uint4*)(gv + 8);
    }

    const float C = 0.125f * 1.4426950408889634f;   // scale * log2(e)

    for (int kt = 0; kt <= qt; ++kt) {
        __syncthreads();
        *(uint4*)&Ksh[srow][sc0]     = ka;
        *(uint4*)&Ksh[srow][sc0 + 8] = kb_;
        *(uint4*)&Vsh[srow][sc0]     = va;
        *(uint4*)&Vsh[srow][sc0 + 8] = vb_;
        __syncthreads();

        if (kt < qt) {     // prefetch next tile; latency hidden by compute
            const ushort* gk = kbase + (size_t)((kt + 1) * 64 + srow) * 64 + sc0;
            ka  = *(const uint4*)gk;
            kb_ = *(const uint4*)(gk + 8);
            const ushort* gv = vbase + (size_t)srow * 2048 + (kt + 1) * 64 + sc0;
            va  = *(const uint4*)gv;
            vb_ = *(const uint4*)(gv + 8);
        }

        // --- scores, swapped: sc[j][r] = S[k = kt*64+j*16+quad*4+r][q = li] ---
        f32x4 sc[4];
        __builtin_amdgcn_s_setprio(1);
#pragma unroll
        for (int j = 0; j < 4; j++) {
            bfrag kb0 = *(const bfrag*)&Ksh[j * 16 + li][quad * 8];
            bfrag kb1 = *(const bfrag*)&Ksh[j * 16 + li][quad * 8 + 32];
            f32x4 z = (f32x4){0.f, 0.f, 0.f, 0.f};
            z = MFMA16(kb0, qa0, z, 0, 0, 0);
            z = MFMA16(kb1, qa1, z, 0, 0, 0);
            sc[j] = z;
        }
        __builtin_amdgcn_s_setprio(0);

        // --- causal mask: only the diagonal tile needs it ---
        if (kt == qt) {
#pragma unroll
            for (int j = 0; j < 4; j++) {
                int kg0 = kt * 64 + j * 16 + quad * 4;
#pragma unroll
                for (int r = 0; r < 4; r++)
                    sc[j][r] = (kg0 + r <= qrow) ? sc[j][r] : -3.0e38f;
            }
        }

        // --- P = exp2(sc*C); lane's 4 values per j are consecutive in k ---
        float rs = 0.f;
#pragma unroll
        for (int j = 0; j < 4; j++) {
            ushort pk[4];
#pragma unroll
            for (int r = 0; r < 4; r++) {
                float pv = exp2f(sc[j][r] * C);
                uint pu = __float_as_uint(pv);
                pk[r] = (ushort)(pu >> 16);
                rs += __uint_as_float(pu & 0xffff0000u);  // consistent w/ P
            }
            *(ushort4*)&Psh[w][li][j * 16 + quad * 4] = *(ushort4*)pk;
        }
        // complete row-sum for q=li across the 4 quads
        rs += __shfl_xor(rs, 16);
        rs += __shfl_xor(rs, 32);
        lrow += rs;

        // --- P: LDS -> A-fragment (wave-private Psh) ---
        asm volatile("s_waitcnt lgkmcnt(0)" ::: "memory");
        bfrag pa0 = *(const bfrag*)&Psh[w][li][quad * 8];
        bfrag pa1 = *(const bfrag*)&Psh[w][li][quad * 8 + 32];

        __builtin_amdgcn_s_setprio(1);
#pragma unroll
        for (int j = 0; j < 4; j++) {
            bfrag vb0 = *(const bfrag*)&Vsh[j * 16 + li][quad * 8];
            bfrag vb1 = *(const bfrag*)&Vsh[j * 16 + li][quad * 8 + 32];
            o[j] = MFMA16(pa0, vb0, o[j], 0, 0, 0);
            o[j] = MFMA16(pa1, vb1, o[j], 0, 0, 0);
        }
        __builtin_amdgcn_s_setprio(0);
    }

    // epilogue: redistribute l (held at lane li == q) to q = quad*4+r
    float lf[4];
#pragma unroll
    for (int r = 0; r < 4; r++)
        lf[r] = __shfl(lrow, (lane & 48) + quad * 4 + r);

#pragma unroll
    for (int j = 0; j < 4; j++)
#pragma unroll
        for (int r = 0; r < 4; r++) {
            int s = qt * 64 + w * 16 + quad * 4 + r;
            out[(size_t)(b * 2048 + s) * 1024 + h * 64 + j * 16 + li] =
                o[j][r] / lf[r];
        }
}

// ---------------------------------------------------------------------------
extern "C" void kernel_launch(void* const* d_in, const int* in_sizes, int n_in,
                              void* d_out, int out_size, void* d_ws, size_t ws_size,
                              hipStream_t stream)
{
    (void)in_sizes; (void)n_in; (void)out_size; (void)ws_size;
    const float* x   = (const float*)d_in[0];   // (2,2048,1024) f32
    const float* wq  = (const float*)d_in[1];   // (1024,1024)  f32
    const float* wkv = (const float*)d_in[2];   // (2048,1024)  f32
    // d_in[3] = causal mask — computed analytically

    ushort* xb = (ushort*)d_ws;                       // 4096x1024 bf16
    ushort* wb = xb + (size_t)4096 * 1024;            // 3072x1024 bf16
    float2* tab = (float2*)(wb + (size_t)3072 * 1024); // 2048x32 (cos,sin)
    ushort* Qb = (ushort*)(tab + 65536);              // (B,H,S,Hd)
    ushort* Kb = Qb + (size_t)2 * 16 * 2048 * 64;     // (B,H,S,Hd)
    ushort* Vt = Kb + (size_t)2 * 16 * 2048 * 64;     // (B,H,Hd,S)
    float* out = (float*)d_out;                       // f32 output

    cvt_rope<<<3840, 256, 0, stream>>>(x, wq, wkv, xb, wb, tab);
    dim3 g1(32, 24);
    gemm_qkv<<<g1, 256, 0, stream>>>(xb, wb, tab, Qb, Kb, Vt);
    dim3 g4(32, 32);
    attn<<<g4, 256, 0, stream>>>(Qb, Kb, Vt, out);
}